// Round 14
// baseline (530.738 us; speedup 1.0000x reference)
//
#include <hip/hip_runtime.h>

// ---------------- workspace layout (float offsets) ----------------
#define OFF_X     0          // x_flat [32][46656]
#define OFF_CUR1  1492992    // [32][1000]
#define OFF_MEM1  1524992    // [32][1000]  (slot A)
#define OFF_MEM2  1556992    // [32][1000]  (slot A)
#define OFF_MEM3  1588992    // [32][1000]  (slot A)
#define OFF_MEMR  1844992    // [32][100]   (slot A)
#define OFF_SPKR  1848192    // [32][100]   (slot A)
#define OFF_MEMO  1851392    // [32]
#define OFF_PATT  1851424    // [32][8]
#define OFF_CNT   1851680    // [5][4] spike counters
#define OFF_OACC  1851700    // [32]
#define OFF_SC    1851732    // total, reg
#define OFF_TICK  1851736    // [5] uint ticket counters (one per step)
#define OFF_PART  1851744    // gemm1 partials [nchunk<=729][32][1000]
// step-loop buffers (overlay the gemm1 partial region after it's consumed)
#define OFF_PG2   OFF_PART               // [25][32][1000]
#define OFF_PG3   (OFF_PART + 800000)    // [25][32][1000]
#define OFF_PKK   (OFF_PART + 1600000)   // [25][32][1000]
#define OFF_PVV   (OFF_PART + 2400000)   // [25][32][1000]
#define OFF_M2B   (OFF_PART + 3200000)   // [32][1000] mem2 slot B
#define OFF_M3B   (OFF_PART + 3232000)   // [32][1000] mem3 slot B
#define OFF_M1B   (OFF_PART + 3264000)   // [32][1000] mem1 slot B
#define OFF_SPK1  (OFF_PART + 3296000)   // [32][1000] spk1 (first leaky spike)
#define OFF_MRB   (OFF_PART + 3328000)   // [32][100] memr slot B
#define OFF_SRB   (OFF_PART + 3331200)   // [32][100] spkr slot B

static constexpr float kBETA  = 0.8f;
static constexpr float kTHR   = 0.5f;
static constexpr float kBETAR = 0.95f;
static constexpr float kTHRR  = 1.0f;
static constexpr float kLM    = 0.0058f;

// ---------------- init: zero all persistent state ----------------
__global__ void k_init(float* ws) {
    int idx = blockIdx.x * 256 + threadIdx.x;
    if (idx < 96000) {
        ws[OFF_MEM1 + idx] = 0.f;                 // mem1, mem2, mem3 (slot A)
    } else {
        int j = idx - 96000;
        if (j < 6752) ws[OFF_MEMR + j] = 0.f;     // memr/spkr A .. sc + tick
    }
}

// ---------------- patch embed: one block per (batch, patch-row) ----------------
__global__ __launch_bounds__(64) void k_patch(
    const float* __restrict__ data, const float* __restrict__ Wpe,
    const float* __restrict__ bpe, const float* __restrict__ pos,
    float* __restrict__ xf)
{
    int b = blockIdx.x, pr = blockIdx.y;
    int tid = threadIdx.x;
    const float* db = data + (size_t)b * 50176 + pr * 1792;  // input row pr*8
    float bb = bpe[tid];
    float acc[27];
    #pragma unroll
    for (int pc = 0; pc < 27; ++pc)
        acc[pc] = bb + pos[(pr * 27 + pc) * 64 + tid];
    #pragma unroll 2
    for (int c = 0; c < 256; ++c) {
        float w = Wpe[c * 64 + tid];
        const float* row = db + (c >> 4) * 224 + (c & 15);
        #pragma unroll
        for (int pc = 0; pc < 27; ++pc)
            acc[pc] = fmaf(row[pc * 8], w, acc[pc]);
    }
    size_t obase = (size_t)b * 46656 + (size_t)pr * 27 * 64 + tid;
    #pragma unroll
    for (int pc = 0; pc < 27; ++pc)
        xf[obase + (size_t)pc * 64] = acc[pc];
}

// ---------------- big GEMM partials: W1 once, 2 cols/thread, tpc=1 -> 1458 blocks ----------------
// 5.7 waves/SIMD (was 2.85 at tpc=2); same FMA:LDS mix, same W1-read-once property.
__global__ __launch_bounds__(256) void k_gemm1_part(
    const float* __restrict__ xf, const float* __restrict__ W1,
    float* __restrict__ part, int tpc)
{
    int chunk = blockIdx.x;
    int hg = blockIdx.y;
    int t0 = chunk * tpc;
    int t1 = t0 + tpc; if (t1 > 729) t1 = 729;
    int tid = threadIdx.x;
    __shared__ float xs[2048];           // [32 b][64 i]
    float acc[32][2];
    #pragma unroll
    for (int b = 0; b < 32; ++b) { acc[b][0] = 0.f; acc[b][1] = 0.f; }

    const int hbase = hg * 500;
    const bool ok1 = (tid + 256) < 500;  // second col valid
    const int h0 = hbase + tid;
    const int h1 = hbase + (ok1 ? tid + 256 : 0);
    for (int tt = t0; tt < t1; ++tt) {
        int i0 = tt * 64;
        __syncthreads();
        for (int l = tid; l < 2048; l += 256)
            xs[l] = xf[(size_t)(l >> 6) * 46656 + i0 + (l & 63)];
        __syncthreads();
        for (int ii4 = 0; ii4 < 16; ++ii4) {
            int i = i0 + ii4 * 4;
            const float* c0 = W1 + (size_t)i * 1000 + h0;
            const float* c1 = W1 + (size_t)i * 1000 + h1;
            float w0a = c0[0], w1a = c0[1000], w2a = c0[2000], w3a = c0[3000];
            float w0b = ok1 ? c1[0]    : 0.f;
            float w1b = ok1 ? c1[1000] : 0.f;
            float w2b = ok1 ? c1[2000] : 0.f;
            float w3b = ok1 ? c1[3000] : 0.f;
            #pragma unroll
            for (int b = 0; b < 32; ++b) {
                float4 xv = *reinterpret_cast<const float4*>(&xs[b * 64 + ii4 * 4]);
                float a0 = acc[b][0], a1 = acc[b][1];
                a0 = fmaf(xv.x, w0a, a0);  a1 = fmaf(xv.x, w0b, a1);
                a0 = fmaf(xv.y, w1a, a0);  a1 = fmaf(xv.y, w1b, a1);
                a0 = fmaf(xv.z, w2a, a0);  a1 = fmaf(xv.z, w2b, a1);
                a0 = fmaf(xv.w, w3a, a0);  a1 = fmaf(xv.w, w3b, a1);
                acc[b][0] = a0; acc[b][1] = a1;
            }
        }
    }
    float* pc = part + (size_t)chunk * 32000 + hbase;
    #pragma unroll
    for (int b = 0; b < 32; ++b) {
        pc[b * 1000 + tid] = acc[b][0];
        if (ok1) pc[b * 1000 + tid + 256] = acc[b][1];
    }
}

// ---------------- reduce with 8-way ILP on the (now 729-deep) chunk chain ----------------
__global__ void k_gemm1_reduce(const float* __restrict__ part,
                               const float* __restrict__ b1,
                               float* __restrict__ cur1, int nchunk)
{
    int idx = blockIdx.x * 128 + threadIdx.x;   // 250 blocks x 128
    if (idx >= 32000) return;
    int h = idx % 1000;
    float a0 = b1[h], a1 = 0.f, a2 = 0.f, a3 = 0.f;
    float a4 = 0.f, a5 = 0.f, a6 = 0.f, a7 = 0.f;
    int c = 0;
    for (; c + 8 <= nchunk; c += 8) {
        a0 += part[(size_t)c * 32000 + idx];
        a1 += part[(size_t)(c + 1) * 32000 + idx];
        a2 += part[(size_t)(c + 2) * 32000 + idx];
        a3 += part[(size_t)(c + 3) * 32000 + idx];
        a4 += part[(size_t)(c + 4) * 32000 + idx];
        a5 += part[(size_t)(c + 5) * 32000 + idx];
        a6 += part[(size_t)(c + 6) * 32000 + idx];
        a7 += part[(size_t)(c + 7) * 32000 + idx];
    }
    for (; c < nchunk; ++c) a0 += part[(size_t)c * 32000 + idx];
    cur1[idx] = ((a0 + a1) + (a2 + a3)) + ((a4 + a5) + (a6 + a7));
}

// ---------------- layer-1 GEMM with double-leaky computed in staging ----------------
// grid (8 hb, 25 kc, 8 bg) = 1600 blocks (6.25 waves/SIMD). Each block computes the
// double-leaky for its own 160-elem slice (4 batches x 40 j); hb==0 writes state.
__global__ __launch_bounds__(256) void k_gsp(
    const float* __restrict__ cur1, const float* __restrict__ mem1_old,
    float* __restrict__ mem1_new, float* __restrict__ spk1_out,
    const float* __restrict__ W, float* __restrict__ part, float* cnt0)
{
    int hb = blockIdx.x, kc = blockIdx.y, bg = blockIdx.z;
    int tid = threadIdx.x;
    int j0 = kc * 40;
    __shared__ __align__(16) float al[160];      // [40 jj][4 b]
    __shared__ float redg[4 * 128];
    __shared__ float csum[4];
    float localc = 0.f;
    if (tid < 160) {
        int jj = tid % 40, bi = tid / 40;
        int idx = (bg * 4 + bi) * 1000 + j0 + jj;
        float m = mem1_old[idx], c = cur1[idx];
        float r1 = (m - kTHR > 0.f) ? kTHR : 0.f;
        float ma = __fsub_rn(__fadd_rn(__fmul_rn(kBETA, m), c), r1);
        float s1 = (ma - kTHR > 0.f) ? 1.f : 0.f;
        float r2 = __fmul_rn(s1, kTHR);
        float mb = __fsub_rn(__fadd_rn(__fmul_rn(kBETA, ma), c), r2);
        float s1b = (mb - kTHR > 0.f) ? 1.f : 0.f;
        al[jj * 4 + bi] = s1b;
        if (hb == 0) { mem1_new[idx] = mb; spk1_out[idx] = s1; localc = s1; }
    }
    for (int off = 32; off; off >>= 1) localc += __shfl_down(localc, off, 64);
    if ((tid & 63) == 0) csum[tid >> 6] = localc;
    __syncthreads();
    if (hb == 0 && tid == 0) {
        float tot = csum[0] + csum[1] + csum[2] + csum[3];
        if (tot != 0.f) atomicAdd(cnt0, tot);
    }
    int ks = tid >> 7, hh = tid & 127;
    float acc[4] = {0.f, 0.f, 0.f, 0.f};
    if (hh < 125) {
        int h = hb * 125 + hh;
        const float* Wp = W + (size_t)(j0 + ks * 20) * 1000 + h;
        const float4* abase = reinterpret_cast<const float4*>(&al[ks * 20 * 4]);
        #pragma unroll 4
        for (int jj = 0; jj < 20; ++jj) {
            float w = Wp[(size_t)jj * 1000];
            float4 av = abase[jj];
            acc[0] = fmaf(av.x, w, acc[0]);
            acc[1] = fmaf(av.y, w, acc[1]);
            acc[2] = fmaf(av.z, w, acc[2]);
            acc[3] = fmaf(av.w, w, acc[3]);
        }
    }
    if (ks == 1 && hh < 125) {
        #pragma unroll
        for (int b = 0; b < 4; ++b) redg[b * 128 + hh] = acc[b];
    }
    __syncthreads();
    if (ks == 0 && hh < 125) {
        int h = hb * 125 + hh;
        float* pp = part + (size_t)kc * 32000 + (size_t)(bg * 4) * 1000 + h;
        #pragma unroll
        for (int b = 0; b < 4; ++b) pp[(size_t)b * 1000] = acc[b] + redg[b * 128 + hh];
    }
}

// ---------------- reduce(prev partials)+leaky staged in LDS, then split GEMM ----------------
template <bool COUNT>
__global__ __launch_bounds__(256) void k_gspred(
    const float* __restrict__ pin, const float* __restrict__ bias,
    const float* __restrict__ mem_old, float* __restrict__ mem_new,
    const float* __restrict__ W, float* __restrict__ pout, float* cnt)
{
    int hs = blockIdx.x, kc = blockIdx.y, bg = blockIdx.z;
    int tid = threadIdx.x;
    int j0 = kc * 40;
    __shared__ __align__(16) float al[160];
    __shared__ float redg[4 * 128];
    __shared__ float csum[4];
    float localc = 0.f;
    if (tid < 160) {
        int jj = tid % 40, bi = tid / 40;
        int idx = (bg * 4 + bi) * 1000 + j0 + jj;
        float a = bias[j0 + jj];
        #pragma unroll 5
        for (int c = 0; c < 25; ++c) a += pin[(size_t)c * 32000 + idx];
        float m = mem_old[idx];
        float r = (m - kTHR > 0.f) ? kTHR : 0.f;
        float mn = __fsub_rn(__fadd_rn(__fmul_rn(kBETA, m), a), r);
        float s = (mn - kTHR > 0.f) ? 1.f : 0.f;
        al[jj * 4 + bi] = s;
        if (hs == 0) { mem_new[idx] = mn; localc = s; }
    }
    if (COUNT) {
        for (int off = 32; off; off >>= 1) localc += __shfl_down(localc, off, 64);
        if ((tid & 63) == 0) csum[tid >> 6] = localc;
    }
    __syncthreads();
    if (COUNT && tid == 0 && hs == 0) {
        float tot = csum[0] + csum[1] + csum[2] + csum[3];
        if (tot != 0.f) atomicAdd(cnt, tot);
    }
    int ks = tid >> 7, hh = tid & 127;
    float acc[4] = {0.f, 0.f, 0.f, 0.f};
    if (hh < 125) {
        int h = hs * 125 + hh;
        const float* Wp = W + (size_t)(j0 + ks * 20) * 1000 + h;
        const float4* abase = reinterpret_cast<const float4*>(&al[ks * 20 * 4]);
        #pragma unroll 4
        for (int jj = 0; jj < 20; ++jj) {
            float w = Wp[(size_t)jj * 1000];
            float4 av = abase[jj];
            acc[0] = fmaf(av.x, w, acc[0]);
            acc[1] = fmaf(av.y, w, acc[1]);
            acc[2] = fmaf(av.z, w, acc[2]);
            acc[3] = fmaf(av.w, w, acc[3]);
        }
    }
    if (ks == 1 && hh < 125) {
        #pragma unroll
        for (int b = 0; b < 4; ++b) redg[b * 128 + hh] = acc[b];
    }
    __syncthreads();
    if (ks == 0 && hh < 125) {
        int h = hs * 125 + hh;
        float* pp = pout + (size_t)kc * 32000 + (size_t)(bg * 4) * 1000 + h;
        #pragma unroll
        for (int b = 0; b < 4; ++b) pp[(size_t)b * 1000] = acc[b] + redg[b * 128 + hh];
    }
}

// dual-weight variant: layer-3 reduce+leaky(+count) staged, then K and V partials
__global__ __launch_bounds__(256) void k_gspred_kv(
    const float* __restrict__ pin, const float* __restrict__ bias,
    const float* __restrict__ mem_old, float* __restrict__ mem_new,
    const float* __restrict__ Wk, const float* __restrict__ Wv,
    float* __restrict__ pk, float* __restrict__ pv, float* cnt)
{
    int hs = blockIdx.x, kc = blockIdx.y, bg = blockIdx.z;
    int tid = threadIdx.x;
    int j0 = kc * 40;
    __shared__ __align__(16) float al[160];
    __shared__ float redk[4 * 128];
    __shared__ float redv[4 * 128];
    __shared__ float csum[4];
    float localc = 0.f;
    if (tid < 160) {
        int jj = tid % 40, bi = tid / 40;
        int idx = (bg * 4 + bi) * 1000 + j0 + jj;
        float a = bias[j0 + jj];
        #pragma unroll 5
        for (int c = 0; c < 25; ++c) a += pin[(size_t)c * 32000 + idx];
        float m = mem_old[idx];
        float r = (m - kTHR > 0.f) ? kTHR : 0.f;
        float mn = __fsub_rn(__fadd_rn(__fmul_rn(kBETA, m), a), r);
        float s = (mn - kTHR > 0.f) ? 1.f : 0.f;
        al[jj * 4 + bi] = s;
        if (hs == 0) { mem_new[idx] = mn; localc = s; }
    }
    for (int off = 32; off; off >>= 1) localc += __shfl_down(localc, off, 64);
    if ((tid & 63) == 0) csum[tid >> 6] = localc;
    __syncthreads();
    if (tid == 0 && hs == 0) {
        float tot = csum[0] + csum[1] + csum[2] + csum[3];
        if (tot != 0.f) atomicAdd(cnt, tot);
    }
    int ks = tid >> 7, hh = tid & 127;
    float ak[4] = {0.f, 0.f, 0.f, 0.f};
    float av2[4] = {0.f, 0.f, 0.f, 0.f};
    if (hh < 125) {
        int h = hs * 125 + hh;
        const float* wkp = Wk + (size_t)(j0 + ks * 20) * 1000 + h;
        const float* wvp = Wv + (size_t)(j0 + ks * 20) * 1000 + h;
        const float4* abase = reinterpret_cast<const float4*>(&al[ks * 20 * 4]);
        #pragma unroll 4
        for (int jj = 0; jj < 20; ++jj) {
            float wk = wkp[(size_t)jj * 1000];
            float wv = wvp[(size_t)jj * 1000];
            float4 av = abase[jj];
            ak[0] = fmaf(av.x, wk, ak[0]);  av2[0] = fmaf(av.x, wv, av2[0]);
            ak[1] = fmaf(av.y, wk, ak[1]);  av2[1] = fmaf(av.y, wv, av2[1]);
            ak[2] = fmaf(av.z, wk, ak[2]);  av2[2] = fmaf(av.z, wv, av2[2]);
            ak[3] = fmaf(av.w, wk, ak[3]);  av2[3] = fmaf(av.w, wv, av2[3]);
        }
    }
    if (ks == 1 && hh < 125) {
        #pragma unroll
        for (int b = 0; b < 4; ++b) { redk[b * 128 + hh] = ak[b]; redv[b * 128 + hh] = av2[b]; }
    }
    __syncthreads();
    if (ks == 0 && hh < 125) {
        int h = hs * 125 + hh;
        float* ppk = pk + (size_t)kc * 32000 + (size_t)(bg * 4) * 1000 + h;
        float* ppv = pv + (size_t)kc * 32000 + (size_t)(bg * 4) * 1000 + h;
        #pragma unroll
        for (int b = 0; b < 4; ++b) {
            ppk[(size_t)b * 1000] = ak[b] + redk[b * 128 + hh];
            ppv[(size_t)b * 1000] = av2[b] + redv[b * 128 + hh];
        }
    }
}

// ---------------- attention: RLeaky prologue + K/V reduce + q + 4-way softmax + final ----------------
// Wave-shuffle reductions (kmax/kmin exact; final sum deterministic 8-way).
__global__ __launch_bounds__(512) void k_attnred(
    const float* __restrict__ pkk, const float* __restrict__ pvv,
    const float* __restrict__ bk, const float* __restrict__ bv,
    const float* __restrict__ spk1, const float* __restrict__ WR,
    const float* __restrict__ bR, const float* __restrict__ Vw,
    const float* __restrict__ Vb,
    const float* __restrict__ memr_old, float* __restrict__ memr_new,
    const float* __restrict__ spkr_old, float* __restrict__ spkr_new,
    const float* __restrict__ Wq, const float* __restrict__ bq,
    const float* __restrict__ Wo, const float* __restrict__ bo,
    float* __restrict__ patt, float* __restrict__ memo,
    float* __restrict__ oacc, const float* __restrict__ cnt,
    float* __restrict__ sc, float* __restrict__ dout,
    unsigned int* __restrict__ tick, float* cnt2, int t)
{
    int it = blockIdx.x, b = blockIdx.y;
    int tid = threadIdx.x;
    __shared__ float kk[1000], vv[1000];
    __shared__ float sr[100];
    __shared__ float s1l[1000];
    __shared__ float red2[512];
    __shared__ float pden[512], pnum[512];
    __shared__ float wred[8], wred2[8];
    __shared__ int isLast;

    // ---- RLeaky (4-way 250-chain WR split, R12 order) ----
    for (int l = tid; l < 1000; l += 512) s1l[l] = spk1[b * 1000 + l];
    if (tid < 100) sr[tid] = spkr_old[b * 100 + tid];
    __syncthreads();
    int ks4 = tid >> 7, hh4 = tid & 127;
    float p = 0.f;
    if (hh4 < 100) {
        const float* wp = WR + (size_t)(ks4 * 250) * 100 + hh4;
        int j0r = ks4 * 250;
        #pragma unroll 5
        for (int j = 0; j < 250; ++j) p = fmaf(s1l[j0r + j], wp[(size_t)j * 100], p);
    }
    red2[ks4 * 128 + hh4] = p;
    __syncthreads();
    float snew = 0.f;
    if (tid < 100) {
        float acc = bR[tid] + ((red2[tid] + red2[128 + tid]) + (red2[256 + tid] + red2[384 + tid]));
        float rec = 0.f;
        for (int j = 0; j < 100; ++j) rec = fmaf(sr[j], Vw[j * 100 + tid], rec);
        float m = memr_old[b * 100 + tid];
        float r = (m - kTHRR > 0.f) ? kTHRR : 0.f;
        float mn = __fsub_rn(__fadd_rn(__fadd_rn(__fadd_rn(__fmul_rn(kBETAR, m), acc), rec), Vb[tid]), r);
        snew = (mn - kTHRR > 0.f) ? 1.f : 0.f;
        if (it == 0) { memr_new[b * 100 + tid] = mn; spkr_new[b * 100 + tid] = snew; }
    }
    if (it == 0) {
        unsigned long long mskr = __ballot(snew > 0.5f);
        if ((tid & 63) == 0) {
            int pc2 = __popcll(mskr);
            if (pc2) atomicAdd(cnt2, (float)pc2);
        }
    }
    __syncthreads();
    if (tid < 100) sr[tid] = snew;     // sr now holds spkr_new for the q-GEMM
    __syncthreads();

    // ---- K/V reduce + wave-shuffle max/min ----
    float pmax = -3.4e38f, pmin = 3.4e38f;
    for (int h = tid; h < 1000; h += 512) {
        int idx = b * 1000 + h;
        float ak = bk[h], av = bv[h];
        #pragma unroll 5
        for (int c = 0; c < 25; ++c) {
            ak += pkk[(size_t)c * 32000 + idx];
            av += pvv[(size_t)c * 32000 + idx];
        }
        kk[h] = ak; vv[h] = av;
        pmax = fmaxf(pmax, ak);
        pmin = fminf(pmin, ak);
    }
    for (int off = 32; off; off >>= 1) {
        pmax = fmaxf(pmax, __shfl_down(pmax, off, 64));
        pmin = fminf(pmin, __shfl_down(pmin, off, 64));
    }
    if ((tid & 63) == 0) { wred[tid >> 6] = pmax; wred2[tid >> 6] = pmin; }
    __syncthreads();
    float kmax = wred[0], kmin = wred2[0];
    #pragma unroll
    for (int w = 1; w < 8; ++w) {
        kmax = fmaxf(kmax, wred[w]);
        kmin = fminf(kmin, wred2[w]);
    }

    // ---- 4-way split softmax ----
    int quarter = tid >> 7, lane = tid & 127;
    float den = 0.f, num = 0.f;
    if (lane < 125) {
        int i = it * 125 + lane;
        float qi = bq[i];
        for (int j = 0; j < 100; ++j) qi = fmaf(sr[j], Wq[j * 1000 + i], qi);
        float qs = qi / 31.62277660168379f;   // sqrt(1000)
        float m = (qs >= 0.f) ? qs * kmax : qs * kmin;
        int jb = quarter * 250;
        for (int j = 0; j < 250; ++j) {
            float e = __expf(fmaf(qs, kk[jb + j], -m));
            den += e;
            num = fmaf(e, vv[jb + j], num);
        }
    }
    pden[tid] = den; pnum[tid] = num;
    __syncthreads();
    float pw = 0.f;
    if (tid < 125) {
        float dsum = (pden[tid] + pden[tid + 128]) + (pden[tid + 256] + pden[tid + 384]);
        float nsum = (pnum[tid] + pnum[tid + 128]) + (pnum[tid + 256] + pnum[tid + 384]);
        pw = (nsum / dsum) * Wo[it * 125 + tid];
    }
    for (int off = 32; off; off >>= 1) pw += __shfl_down(pw, off, 64);
    if ((tid & 63) == 0) wred[tid >> 6] = pw;
    __syncthreads();
    if (tid == 0) {
        float tot = ((wred[0] + wred[1]) + (wred[2] + wred[3]))
                  + ((wred[4] + wred[5]) + (wred[6] + wred[7]));
        patt[b * 8 + it] = tot;
    }
    __syncthreads();
    if (tid == 0) {
        __threadfence();
        unsigned r = atomicAdd(tick, 1u);
        isLast = (r == 255u) ? 1 : 0;
    }
    __syncthreads();
    if (isLast && tid < 64) {
        __threadfence();
        float s = 0.f;
        if (tid < 32) {
            float a = bo[0];
            for (int itx = 0; itx < 8; ++itx) a += patt[tid * 8 + itx];
            float m = memo[tid];
            float r = (m - kTHR > 0.f) ? kTHR : 0.f;
            float mn = __fsub_rn(__fadd_rn(__fmul_rn(kBETA, m), a), r);
            memo[tid] = mn;
            s = (mn - kTHR > 0.f) ? 1.f : 0.f;
            float oa = oacc[tid] + s;
            oacc[tid] = oa;
            if (t == 4) dout[tid] = oa / 5.0f;
        }
        unsigned long long msk = __ballot(s > 0.5f);
        float co = (float)__popcll(msk);
        if (tid == 0) {
            float total = sc[0];
            float prev = total;
            total = __fadd_rn(total, __fdiv_rn(cnt[0], 32000.f));
            total = __fadd_rn(total, __fdiv_rn(cnt[1], 32000.f));
            total = __fadd_rn(total, __fdiv_rn(cnt[2], 3200.f));
            total = __fadd_rn(total, __fdiv_rn(co, 32.f));
            float reg = sc[1];
            reg = __fadd_rn(reg, __fmul_rn(kLM, total));
            if (t > 0) reg = __fadd_rn(reg, __fmul_rn(kLM, fabsf(__fsub_rn(total, prev))));
            sc[0] = total; sc[1] = reg;
            if (t == 4) dout[32] = reg / 5.0f;
        }
    }
}

// ---------------- host ----------------
extern "C" void kernel_launch(void* const* d_in, const int* in_sizes, int n_in,
                              void* d_out, int out_size, void* d_ws, size_t ws_size,
                              hipStream_t stream)
{
    const float* data = (const float*)d_in[0];
    const float* Wpe  = (const float*)d_in[1];
    const float* bpe  = (const float*)d_in[2];
    const float* pos  = (const float*)d_in[3];
    const float* W1   = (const float*)d_in[4];
    const float* b1   = (const float*)d_in[5];
    const float* W2   = (const float*)d_in[6];
    const float* b2   = (const float*)d_in[7];
    const float* W3   = (const float*)d_in[8];
    const float* b3   = (const float*)d_in[9];
    const float* WR   = (const float*)d_in[10];
    const float* bR   = (const float*)d_in[11];
    const float* Vw   = (const float*)d_in[12];
    const float* Vb   = (const float*)d_in[13];
    const float* Wq   = (const float*)d_in[14];
    const float* bq   = (const float*)d_in[15];
    const float* Wk   = (const float*)d_in[16];
    const float* bk   = (const float*)d_in[17];
    const float* Wv   = (const float*)d_in[18];
    const float* bv   = (const float*)d_in[19];
    const float* Wo   = (const float*)d_in[20];
    const float* bo   = (const float*)d_in[21];

    float* ws = (float*)d_ws;
    float* dout = (float*)d_out;

    float* xf    = ws + OFF_X;
    float* cur1  = ws + OFF_CUR1;
    float* mem1a = ws + OFF_MEM1;
    float* mem2a = ws + OFF_MEM2;
    float* mem3a = ws + OFF_MEM3;
    float* memra = ws + OFF_MEMR;
    float* spkra = ws + OFF_SPKR;
    float* memo  = ws + OFF_MEMO;
    float* patt  = ws + OFF_PATT;
    float* cntb  = ws + OFF_CNT;
    float* oacc  = ws + OFF_OACC;
    float* sc    = ws + OFF_SC;
    unsigned int* tick = (unsigned int*)(ws + OFF_TICK);
    float* part  = ws + OFF_PART;
    float* pg2   = ws + OFF_PG2;
    float* pg3   = ws + OFF_PG3;
    float* pkk   = ws + OFF_PKK;
    float* pvv   = ws + OFF_PVV;
    float* mem2b = ws + OFF_M2B;
    float* mem3b = ws + OFF_M3B;
    float* mem1b = ws + OFF_M1B;
    float* spk1  = ws + OFF_SPK1;
    float* memrb = ws + OFF_MRB;
    float* spkrb = ws + OFF_SRB;

    // chunk count for the big GEMM: cap 729 (tpc=1) -> 1458 blocks, 93 MB partials
    size_t ws_f = ws_size / 4;
    size_t avail = (ws_f > OFF_PART) ? (ws_f - OFF_PART) : 0;
    long nchunk_l = (long)(avail / 32000);
    int nchunk = (nchunk_l > 729) ? 729 : (int)nchunk_l;
    if (nchunk < 1) nchunk = 1;
    int tpc = (729 + nchunk - 1) / nchunk;
    nchunk = (729 + tpc - 1) / tpc;

    k_init<<<402, 256, 0, stream>>>(ws);
    k_patch<<<dim3(32, 27), 64, 0, stream>>>(data, Wpe, bpe, pos, xf);
    k_gemm1_part<<<dim3(nchunk, 2), 256, 0, stream>>>(xf, W1, part, tpc);
    k_gemm1_reduce<<<250, 128, 0, stream>>>(part, b1, cur1, nchunk);

    for (int t = 0; t < 5; ++t) {
        float* cnt = cntb + t * 4;
        float* m1o = (t & 1) ? mem1b : mem1a;
        float* m1n = (t & 1) ? mem1a : mem1b;
        float* m2o = (t & 1) ? mem2b : mem2a;
        float* m2n = (t & 1) ? mem2a : mem2b;
        float* m3o = (t & 1) ? mem3b : mem3a;
        float* m3n = (t & 1) ? mem3a : mem3b;
        float* mro = (t & 1) ? memrb : memra;
        float* mrn = (t & 1) ? memra : memrb;
        float* sro = (t & 1) ? spkrb : spkra;
        float* srn = (t & 1) ? spkra : spkrb;

        // 1. double-leaky (in staging) + GEMM @ W2 -> pg2
        k_gsp<<<dim3(8, 25, 8), 256, 0, stream>>>(
            cur1, m1o, m1n, spk1, W2, pg2, cnt + 0);
        // 2. reduce pg2 + leaky(mem2) staged, GEMM @ W3 -> pg3
        k_gspred<false><<<dim3(8, 25, 8), 256, 0, stream>>>(
            pg2, b2, m2o, m2n, W3, pg3, nullptr);
        // 3. reduce pg3 + leaky(mem3)(+count) staged, GEMM @ Wk/Wv -> pkk, pvv
        k_gspred_kv<<<dim3(8, 25, 8), 256, 0, stream>>>(
            pg3, b3, m3o, m3n, Wk, Wv, pkk, pvv, cnt + 1);
        // 4. attention: RLeaky prologue + K/V reduce + q + softmax + final
        k_attnred<<<dim3(8, 32), 512, 0, stream>>>(
            pkk, pvv, bk, bv, spk1, WR, bR, Vw, Vb,
            mro, mrn, sro, srn, Wq, bq, Wo, bo,
            patt, memo, oacc, cnt, sc, dout, tick + t, cnt + 2, t);
    }
    (void)in_sizes; (void)n_in; (void)out_size;
}

// Round 15
// 492.900 us; speedup vs baseline: 1.0768x; 1.0768x over previous
//
#include <hip/hip_runtime.h>

// ---------------- workspace layout (float offsets) ----------------
#define OFF_X     0          // x_flat [32][46656]
#define OFF_CUR1  1492992    // [32][1000]
#define OFF_MEM1  1524992    // [32][1000]  (slot A)
#define OFF_MEM2  1556992    // [32][1000]  (slot A)
#define OFF_MEM3  1588992    // [32][1000]  (slot A)
#define OFF_MEMR  1844992    // [32][100]   (slot A)
#define OFF_SPKR  1848192    // [32][100]   (slot A)
#define OFF_MEMO  1851392    // [32]
#define OFF_PATT  1851424    // [32][8]
#define OFF_CNT   1851680    // [5][4] spike counters
#define OFF_OACC  1851700    // [32]
#define OFF_SC    1851732    // total, reg
#define OFF_TICK  1851736    // [5] uint ticket counters (one per step)
#define OFF_PART  1851744    // gemm1 partials [nchunk<=365][32][1000]
// step-loop buffers (overlay the gemm1 partial region after it's consumed)
#define OFF_PG2   OFF_PART               // [25][32][1000]
#define OFF_PG3   (OFF_PART + 800000)    // [25][32][1000]
#define OFF_PKK   (OFF_PART + 1600000)   // [25][32][1000]
#define OFF_PVV   (OFF_PART + 2400000)   // [25][32][1000]
#define OFF_M2B   (OFF_PART + 3200000)   // [32][1000] mem2 slot B
#define OFF_M3B   (OFF_PART + 3232000)   // [32][1000] mem3 slot B
#define OFF_M1B   (OFF_PART + 3264000)   // [32][1000] mem1 slot B
#define OFF_SPK1  (OFF_PART + 3296000)   // [32][1000] spk1 (first leaky spike)
#define OFF_MRB   (OFF_PART + 3328000)   // [32][100] memr slot B
#define OFF_SRB   (OFF_PART + 3331200)   // [32][100] spkr slot B

static constexpr float kBETA  = 0.8f;
static constexpr float kTHR   = 0.5f;
static constexpr float kBETAR = 0.95f;
static constexpr float kTHRR  = 1.0f;
static constexpr float kLM    = 0.0058f;

// ---------------- init: zero all persistent state ----------------
__global__ void k_init(float* ws) {
    int idx = blockIdx.x * 256 + threadIdx.x;
    if (idx < 96000) {
        ws[OFF_MEM1 + idx] = 0.f;                 // mem1, mem2, mem3 (slot A)
    } else {
        int j = idx - 96000;
        if (j < 6752) ws[OFF_MEMR + j] = 0.f;     // memr/spkr A .. sc + tick
    }
}

// ---------------- patch embed: one block per (batch, patch-row) ----------------
__global__ __launch_bounds__(64) void k_patch(
    const float* __restrict__ data, const float* __restrict__ Wpe,
    const float* __restrict__ bpe, const float* __restrict__ pos,
    float* __restrict__ xf)
{
    int b = blockIdx.x, pr = blockIdx.y;
    int tid = threadIdx.x;
    const float* db = data + (size_t)b * 50176 + pr * 1792;  // input row pr*8
    float bb = bpe[tid];
    float acc[27];
    #pragma unroll
    for (int pc = 0; pc < 27; ++pc)
        acc[pc] = bb + pos[(pr * 27 + pc) * 64 + tid];
    #pragma unroll 2
    for (int c = 0; c < 256; ++c) {
        float w = Wpe[c * 64 + tid];
        const float* row = db + (c >> 4) * 224 + (c & 15);
        #pragma unroll
        for (int pc = 0; pc < 27; ++pc)
            acc[pc] = fmaf(row[pc * 8], w, acc[pc]);
    }
    size_t obase = (size_t)b * 46656 + (size_t)pr * 27 * 64 + tid;
    #pragma unroll
    for (int pc = 0; pc < 27; ++pc)
        xf[obase + (size_t)pc * 64] = acc[pc];
}

// ---------------- big GEMM partials: W1 once, 2 cols/thread, tpc=2 -> 730 blocks ----------------
// REVERTED to tpc=2 (R13): tpc=1's 93 MB partial buffer spilled past L2 -> HBM
// round-trip (+92 MB WRITE_SIZE, gemm1 65->111 us). 46.7 MB stays L2/L3-friendly.
__global__ __launch_bounds__(256) void k_gemm1_part(
    const float* __restrict__ xf, const float* __restrict__ W1,
    float* __restrict__ part, int tpc)
{
    int chunk = blockIdx.x;
    int hg = blockIdx.y;
    int t0 = chunk * tpc;
    int t1 = t0 + tpc; if (t1 > 729) t1 = 729;
    int tid = threadIdx.x;
    __shared__ float xs[2048];           // [32 b][64 i]
    float acc[32][2];
    #pragma unroll
    for (int b = 0; b < 32; ++b) { acc[b][0] = 0.f; acc[b][1] = 0.f; }

    const int hbase = hg * 500;
    const bool ok1 = (tid + 256) < 500;  // second col valid
    const int h0 = hbase + tid;
    const int h1 = hbase + (ok1 ? tid + 256 : 0);
    for (int tt = t0; tt < t1; ++tt) {
        int i0 = tt * 64;
        __syncthreads();
        for (int l = tid; l < 2048; l += 256)
            xs[l] = xf[(size_t)(l >> 6) * 46656 + i0 + (l & 63)];
        __syncthreads();
        for (int ii4 = 0; ii4 < 16; ++ii4) {
            int i = i0 + ii4 * 4;
            const float* c0 = W1 + (size_t)i * 1000 + h0;
            const float* c1 = W1 + (size_t)i * 1000 + h1;
            float w0a = c0[0], w1a = c0[1000], w2a = c0[2000], w3a = c0[3000];
            float w0b = ok1 ? c1[0]    : 0.f;
            float w1b = ok1 ? c1[1000] : 0.f;
            float w2b = ok1 ? c1[2000] : 0.f;
            float w3b = ok1 ? c1[3000] : 0.f;
            #pragma unroll
            for (int b = 0; b < 32; ++b) {
                float4 xv = *reinterpret_cast<const float4*>(&xs[b * 64 + ii4 * 4]);
                float a0 = acc[b][0], a1 = acc[b][1];
                a0 = fmaf(xv.x, w0a, a0);  a1 = fmaf(xv.x, w0b, a1);
                a0 = fmaf(xv.y, w1a, a0);  a1 = fmaf(xv.y, w1b, a1);
                a0 = fmaf(xv.z, w2a, a0);  a1 = fmaf(xv.z, w2b, a1);
                a0 = fmaf(xv.w, w3a, a0);  a1 = fmaf(xv.w, w3b, a1);
                acc[b][0] = a0; acc[b][1] = a1;
            }
        }
    }
    float* pc = part + (size_t)chunk * 32000 + hbase;
    #pragma unroll
    for (int b = 0; b < 32; ++b) {
        pc[b * 1000 + tid] = acc[b][0];
        if (ok1) pc[b * 1000 + tid + 256] = acc[b][1];
    }
}

// ---------------- reduce with 8-way ILP on the chunk chain ----------------
__global__ void k_gemm1_reduce(const float* __restrict__ part,
                               const float* __restrict__ b1,
                               float* __restrict__ cur1, int nchunk)
{
    int idx = blockIdx.x * 128 + threadIdx.x;   // 250 blocks x 128
    if (idx >= 32000) return;
    int h = idx % 1000;
    float a0 = b1[h], a1 = 0.f, a2 = 0.f, a3 = 0.f;
    float a4 = 0.f, a5 = 0.f, a6 = 0.f, a7 = 0.f;
    int c = 0;
    for (; c + 8 <= nchunk; c += 8) {
        a0 += part[(size_t)c * 32000 + idx];
        a1 += part[(size_t)(c + 1) * 32000 + idx];
        a2 += part[(size_t)(c + 2) * 32000 + idx];
        a3 += part[(size_t)(c + 3) * 32000 + idx];
        a4 += part[(size_t)(c + 4) * 32000 + idx];
        a5 += part[(size_t)(c + 5) * 32000 + idx];
        a6 += part[(size_t)(c + 6) * 32000 + idx];
        a7 += part[(size_t)(c + 7) * 32000 + idx];
    }
    for (; c < nchunk; ++c) a0 += part[(size_t)c * 32000 + idx];
    cur1[idx] = ((a0 + a1) + (a2 + a3)) + ((a4 + a5) + (a6 + a7));
}

// ---------------- layer-1 GEMM with double-leaky computed in staging ----------------
// grid (8 hb, 25 kc, 8 bg) = 1600 blocks (6.25 waves/SIMD). Each block computes the
// double-leaky for its own 160-elem slice (4 batches x 40 j); hb==0 writes state.
__global__ __launch_bounds__(256) void k_gsp(
    const float* __restrict__ cur1, const float* __restrict__ mem1_old,
    float* __restrict__ mem1_new, float* __restrict__ spk1_out,
    const float* __restrict__ W, float* __restrict__ part, float* cnt0)
{
    int hb = blockIdx.x, kc = blockIdx.y, bg = blockIdx.z;
    int tid = threadIdx.x;
    int j0 = kc * 40;
    __shared__ __align__(16) float al[160];      // [40 jj][4 b]
    __shared__ float redg[4 * 128];
    __shared__ float csum[4];
    float localc = 0.f;
    if (tid < 160) {
        int jj = tid % 40, bi = tid / 40;
        int idx = (bg * 4 + bi) * 1000 + j0 + jj;
        float m = mem1_old[idx], c = cur1[idx];
        float r1 = (m - kTHR > 0.f) ? kTHR : 0.f;
        float ma = __fsub_rn(__fadd_rn(__fmul_rn(kBETA, m), c), r1);
        float s1 = (ma - kTHR > 0.f) ? 1.f : 0.f;
        float r2 = __fmul_rn(s1, kTHR);
        float mb = __fsub_rn(__fadd_rn(__fmul_rn(kBETA, ma), c), r2);
        float s1b = (mb - kTHR > 0.f) ? 1.f : 0.f;
        al[jj * 4 + bi] = s1b;
        if (hb == 0) { mem1_new[idx] = mb; spk1_out[idx] = s1; localc = s1; }
    }
    for (int off = 32; off; off >>= 1) localc += __shfl_down(localc, off, 64);
    if ((tid & 63) == 0) csum[tid >> 6] = localc;
    __syncthreads();
    if (hb == 0 && tid == 0) {
        float tot = csum[0] + csum[1] + csum[2] + csum[3];
        if (tot != 0.f) atomicAdd(cnt0, tot);
    }
    int ks = tid >> 7, hh = tid & 127;
    float acc[4] = {0.f, 0.f, 0.f, 0.f};
    if (hh < 125) {
        int h = hb * 125 + hh;
        const float* Wp = W + (size_t)(j0 + ks * 20) * 1000 + h;
        const float4* abase = reinterpret_cast<const float4*>(&al[ks * 20 * 4]);
        #pragma unroll 4
        for (int jj = 0; jj < 20; ++jj) {
            float w = Wp[(size_t)jj * 1000];
            float4 av = abase[jj];
            acc[0] = fmaf(av.x, w, acc[0]);
            acc[1] = fmaf(av.y, w, acc[1]);
            acc[2] = fmaf(av.z, w, acc[2]);
            acc[3] = fmaf(av.w, w, acc[3]);
        }
    }
    if (ks == 1 && hh < 125) {
        #pragma unroll
        for (int b = 0; b < 4; ++b) redg[b * 128 + hh] = acc[b];
    }
    __syncthreads();
    if (ks == 0 && hh < 125) {
        int h = hb * 125 + hh;
        float* pp = part + (size_t)kc * 32000 + (size_t)(bg * 4) * 1000 + h;
        #pragma unroll
        for (int b = 0; b < 4; ++b) pp[(size_t)b * 1000] = acc[b] + redg[b * 128 + hh];
    }
}

// ---------------- reduce(prev partials)+leaky staged in LDS, then split GEMM ----------------
template <bool COUNT>
__global__ __launch_bounds__(256) void k_gspred(
    const float* __restrict__ pin, const float* __restrict__ bias,
    const float* __restrict__ mem_old, float* __restrict__ mem_new,
    const float* __restrict__ W, float* __restrict__ pout, float* cnt)
{
    int hs = blockIdx.x, kc = blockIdx.y, bg = blockIdx.z;
    int tid = threadIdx.x;
    int j0 = kc * 40;
    __shared__ __align__(16) float al[160];
    __shared__ float redg[4 * 128];
    __shared__ float csum[4];
    float localc = 0.f;
    if (tid < 160) {
        int jj = tid % 40, bi = tid / 40;
        int idx = (bg * 4 + bi) * 1000 + j0 + jj;
        float a = bias[j0 + jj];
        #pragma unroll 5
        for (int c = 0; c < 25; ++c) a += pin[(size_t)c * 32000 + idx];
        float m = mem_old[idx];
        float r = (m - kTHR > 0.f) ? kTHR : 0.f;
        float mn = __fsub_rn(__fadd_rn(__fmul_rn(kBETA, m), a), r);
        float s = (mn - kTHR > 0.f) ? 1.f : 0.f;
        al[jj * 4 + bi] = s;
        if (hs == 0) { mem_new[idx] = mn; localc = s; }
    }
    if (COUNT) {
        for (int off = 32; off; off >>= 1) localc += __shfl_down(localc, off, 64);
        if ((tid & 63) == 0) csum[tid >> 6] = localc;
    }
    __syncthreads();
    if (COUNT && tid == 0 && hs == 0) {
        float tot = csum[0] + csum[1] + csum[2] + csum[3];
        if (tot != 0.f) atomicAdd(cnt, tot);
    }
    int ks = tid >> 7, hh = tid & 127;
    float acc[4] = {0.f, 0.f, 0.f, 0.f};
    if (hh < 125) {
        int h = hs * 125 + hh;
        const float* Wp = W + (size_t)(j0 + ks * 20) * 1000 + h;
        const float4* abase = reinterpret_cast<const float4*>(&al[ks * 20 * 4]);
        #pragma unroll 4
        for (int jj = 0; jj < 20; ++jj) {
            float w = Wp[(size_t)jj * 1000];
            float4 av = abase[jj];
            acc[0] = fmaf(av.x, w, acc[0]);
            acc[1] = fmaf(av.y, w, acc[1]);
            acc[2] = fmaf(av.z, w, acc[2]);
            acc[3] = fmaf(av.w, w, acc[3]);
        }
    }
    if (ks == 1 && hh < 125) {
        #pragma unroll
        for (int b = 0; b < 4; ++b) redg[b * 128 + hh] = acc[b];
    }
    __syncthreads();
    if (ks == 0 && hh < 125) {
        int h = hs * 125 + hh;
        float* pp = pout + (size_t)kc * 32000 + (size_t)(bg * 4) * 1000 + h;
        #pragma unroll
        for (int b = 0; b < 4; ++b) pp[(size_t)b * 1000] = acc[b] + redg[b * 128 + hh];
    }
}

// dual-weight variant: layer-3 reduce+leaky(+count) staged, then K and V partials
__global__ __launch_bounds__(256) void k_gspred_kv(
    const float* __restrict__ pin, const float* __restrict__ bias,
    const float* __restrict__ mem_old, float* __restrict__ mem_new,
    const float* __restrict__ Wk, const float* __restrict__ Wv,
    float* __restrict__ pk, float* __restrict__ pv, float* cnt)
{
    int hs = blockIdx.x, kc = blockIdx.y, bg = blockIdx.z;
    int tid = threadIdx.x;
    int j0 = kc * 40;
    __shared__ __align__(16) float al[160];
    __shared__ float redk[4 * 128];
    __shared__ float redv[4 * 128];
    __shared__ float csum[4];
    float localc = 0.f;
    if (tid < 160) {
        int jj = tid % 40, bi = tid / 40;
        int idx = (bg * 4 + bi) * 1000 + j0 + jj;
        float a = bias[j0 + jj];
        #pragma unroll 5
        for (int c = 0; c < 25; ++c) a += pin[(size_t)c * 32000 + idx];
        float m = mem_old[idx];
        float r = (m - kTHR > 0.f) ? kTHR : 0.f;
        float mn = __fsub_rn(__fadd_rn(__fmul_rn(kBETA, m), a), r);
        float s = (mn - kTHR > 0.f) ? 1.f : 0.f;
        al[jj * 4 + bi] = s;
        if (hs == 0) { mem_new[idx] = mn; localc = s; }
    }
    for (int off = 32; off; off >>= 1) localc += __shfl_down(localc, off, 64);
    if ((tid & 63) == 0) csum[tid >> 6] = localc;
    __syncthreads();
    if (tid == 0 && hs == 0) {
        float tot = csum[0] + csum[1] + csum[2] + csum[3];
        if (tot != 0.f) atomicAdd(cnt, tot);
    }
    int ks = tid >> 7, hh = tid & 127;
    float ak[4] = {0.f, 0.f, 0.f, 0.f};
    float av2[4] = {0.f, 0.f, 0.f, 0.f};
    if (hh < 125) {
        int h = hs * 125 + hh;
        const float* wkp = Wk + (size_t)(j0 + ks * 20) * 1000 + h;
        const float* wvp = Wv + (size_t)(j0 + ks * 20) * 1000 + h;
        const float4* abase = reinterpret_cast<const float4*>(&al[ks * 20 * 4]);
        #pragma unroll 4
        for (int jj = 0; jj < 20; ++jj) {
            float wk = wkp[(size_t)jj * 1000];
            float wv = wvp[(size_t)jj * 1000];
            float4 av = abase[jj];
            ak[0] = fmaf(av.x, wk, ak[0]);  av2[0] = fmaf(av.x, wv, av2[0]);
            ak[1] = fmaf(av.y, wk, ak[1]);  av2[1] = fmaf(av.y, wv, av2[1]);
            ak[2] = fmaf(av.z, wk, ak[2]);  av2[2] = fmaf(av.z, wv, av2[2]);
            ak[3] = fmaf(av.w, wk, ak[3]);  av2[3] = fmaf(av.w, wv, av2[3]);
        }
    }
    if (ks == 1 && hh < 125) {
        #pragma unroll
        for (int b = 0; b < 4; ++b) { redk[b * 128 + hh] = ak[b]; redv[b * 128 + hh] = av2[b]; }
    }
    __syncthreads();
    if (ks == 0 && hh < 125) {
        int h = hs * 125 + hh;
        float* ppk = pk + (size_t)kc * 32000 + (size_t)(bg * 4) * 1000 + h;
        float* ppv = pv + (size_t)kc * 32000 + (size_t)(bg * 4) * 1000 + h;
        #pragma unroll
        for (int b = 0; b < 4; ++b) {
            ppk[(size_t)b * 1000] = ak[b] + redk[b * 128 + hh];
            ppv[(size_t)b * 1000] = av2[b] + redv[b * 128 + hh];
        }
    }
}

// ---------------- attention: RLeaky prologue + K/V reduce + q + 4-way softmax + final ----------------
// Wave-shuffle reductions (kmax/kmin exact; final sum deterministic 8-way).
__global__ __launch_bounds__(512) void k_attnred(
    const float* __restrict__ pkk, const float* __restrict__ pvv,
    const float* __restrict__ bk, const float* __restrict__ bv,
    const float* __restrict__ spk1, const float* __restrict__ WR,
    const float* __restrict__ bR, const float* __restrict__ Vw,
    const float* __restrict__ Vb,
    const float* __restrict__ memr_old, float* __restrict__ memr_new,
    const float* __restrict__ spkr_old, float* __restrict__ spkr_new,
    const float* __restrict__ Wq, const float* __restrict__ bq,
    const float* __restrict__ Wo, const float* __restrict__ bo,
    float* __restrict__ patt, float* __restrict__ memo,
    float* __restrict__ oacc, const float* __restrict__ cnt,
    float* __restrict__ sc, float* __restrict__ dout,
    unsigned int* __restrict__ tick, float* cnt2, int t)
{
    int it = blockIdx.x, b = blockIdx.y;
    int tid = threadIdx.x;
    __shared__ float kk[1000], vv[1000];
    __shared__ float sr[100];
    __shared__ float s1l[1000];
    __shared__ float red2[512];
    __shared__ float pden[512], pnum[512];
    __shared__ float wred[8], wred2[8];
    __shared__ int isLast;

    // ---- RLeaky (4-way 250-chain WR split, R12 order) ----
    for (int l = tid; l < 1000; l += 512) s1l[l] = spk1[b * 1000 + l];
    if (tid < 100) sr[tid] = spkr_old[b * 100 + tid];
    __syncthreads();
    int ks4 = tid >> 7, hh4 = tid & 127;
    float p = 0.f;
    if (hh4 < 100) {
        const float* wp = WR + (size_t)(ks4 * 250) * 100 + hh4;
        int j0r = ks4 * 250;
        #pragma unroll 5
        for (int j = 0; j < 250; ++j) p = fmaf(s1l[j0r + j], wp[(size_t)j * 100], p);
    }
    red2[ks4 * 128 + hh4] = p;
    __syncthreads();
    float snew = 0.f;
    if (tid < 100) {
        float acc = bR[tid] + ((red2[tid] + red2[128 + tid]) + (red2[256 + tid] + red2[384 + tid]));
        float rec = 0.f;
        for (int j = 0; j < 100; ++j) rec = fmaf(sr[j], Vw[j * 100 + tid], rec);
        float m = memr_old[b * 100 + tid];
        float r = (m - kTHRR > 0.f) ? kTHRR : 0.f;
        float mn = __fsub_rn(__fadd_rn(__fadd_rn(__fadd_rn(__fmul_rn(kBETAR, m), acc), rec), Vb[tid]), r);
        snew = (mn - kTHRR > 0.f) ? 1.f : 0.f;
        if (it == 0) { memr_new[b * 100 + tid] = mn; spkr_new[b * 100 + tid] = snew; }
    }
    if (it == 0) {
        unsigned long long mskr = __ballot(snew > 0.5f);
        if ((tid & 63) == 0) {
            int pc2 = __popcll(mskr);
            if (pc2) atomicAdd(cnt2, (float)pc2);
        }
    }
    __syncthreads();
    if (tid < 100) sr[tid] = snew;     // sr now holds spkr_new for the q-GEMM
    __syncthreads();

    // ---- K/V reduce + wave-shuffle max/min ----
    float pmax = -3.4e38f, pmin = 3.4e38f;
    for (int h = tid; h < 1000; h += 512) {
        int idx = b * 1000 + h;
        float ak = bk[h], av = bv[h];
        #pragma unroll 5
        for (int c = 0; c < 25; ++c) {
            ak += pkk[(size_t)c * 32000 + idx];
            av += pvv[(size_t)c * 32000 + idx];
        }
        kk[h] = ak; vv[h] = av;
        pmax = fmaxf(pmax, ak);
        pmin = fminf(pmin, ak);
    }
    for (int off = 32; off; off >>= 1) {
        pmax = fmaxf(pmax, __shfl_down(pmax, off, 64));
        pmin = fminf(pmin, __shfl_down(pmin, off, 64));
    }
    if ((tid & 63) == 0) { wred[tid >> 6] = pmax; wred2[tid >> 6] = pmin; }
    __syncthreads();
    float kmax = wred[0], kmin = wred2[0];
    #pragma unroll
    for (int w = 1; w < 8; ++w) {
        kmax = fmaxf(kmax, wred[w]);
        kmin = fminf(kmin, wred2[w]);
    }

    // ---- 4-way split softmax ----
    int quarter = tid >> 7, lane = tid & 127;
    float den = 0.f, num = 0.f;
    if (lane < 125) {
        int i = it * 125 + lane;
        float qi = bq[i];
        for (int j = 0; j < 100; ++j) qi = fmaf(sr[j], Wq[j * 1000 + i], qi);
        float qs = qi / 31.62277660168379f;   // sqrt(1000)
        float m = (qs >= 0.f) ? qs * kmax : qs * kmin;
        int jb = quarter * 250;
        for (int j = 0; j < 250; ++j) {
            float e = __expf(fmaf(qs, kk[jb + j], -m));
            den += e;
            num = fmaf(e, vv[jb + j], num);
        }
    }
    pden[tid] = den; pnum[tid] = num;
    __syncthreads();
    float pw = 0.f;
    if (tid < 125) {
        float dsum = (pden[tid] + pden[tid + 128]) + (pden[tid + 256] + pden[tid + 384]);
        float nsum = (pnum[tid] + pnum[tid + 128]) + (pnum[tid + 256] + pnum[tid + 384]);
        pw = (nsum / dsum) * Wo[it * 125 + tid];
    }
    for (int off = 32; off; off >>= 1) pw += __shfl_down(pw, off, 64);
    if ((tid & 63) == 0) wred[tid >> 6] = pw;
    __syncthreads();
    if (tid == 0) {
        float tot = ((wred[0] + wred[1]) + (wred[2] + wred[3]))
                  + ((wred[4] + wred[5]) + (wred[6] + wred[7]));
        patt[b * 8 + it] = tot;
    }
    __syncthreads();
    if (tid == 0) {
        __threadfence();
        unsigned r = atomicAdd(tick, 1u);
        isLast = (r == 255u) ? 1 : 0;
    }
    __syncthreads();
    if (isLast && tid < 64) {
        __threadfence();
        float s = 0.f;
        if (tid < 32) {
            float a = bo[0];
            for (int itx = 0; itx < 8; ++itx) a += patt[tid * 8 + itx];
            float m = memo[tid];
            float r = (m - kTHR > 0.f) ? kTHR : 0.f;
            float mn = __fsub_rn(__fadd_rn(__fmul_rn(kBETA, m), a), r);
            memo[tid] = mn;
            s = (mn - kTHR > 0.f) ? 1.f : 0.f;
            float oa = oacc[tid] + s;
            oacc[tid] = oa;
            if (t == 4) dout[tid] = oa / 5.0f;
        }
        unsigned long long msk = __ballot(s > 0.5f);
        float co = (float)__popcll(msk);
        if (tid == 0) {
            float total = sc[0];
            float prev = total;
            total = __fadd_rn(total, __fdiv_rn(cnt[0], 32000.f));
            total = __fadd_rn(total, __fdiv_rn(cnt[1], 32000.f));
            total = __fadd_rn(total, __fdiv_rn(cnt[2], 3200.f));
            total = __fadd_rn(total, __fdiv_rn(co, 32.f));
            float reg = sc[1];
            reg = __fadd_rn(reg, __fmul_rn(kLM, total));
            if (t > 0) reg = __fadd_rn(reg, __fmul_rn(kLM, fabsf(__fsub_rn(total, prev))));
            sc[0] = total; sc[1] = reg;
            if (t == 4) dout[32] = reg / 5.0f;
        }
    }
}

// ---------------- host ----------------
extern "C" void kernel_launch(void* const* d_in, const int* in_sizes, int n_in,
                              void* d_out, int out_size, void* d_ws, size_t ws_size,
                              hipStream_t stream)
{
    const float* data = (const float*)d_in[0];
    const float* Wpe  = (const float*)d_in[1];
    const float* bpe  = (const float*)d_in[2];
    const float* pos  = (const float*)d_in[3];
    const float* W1   = (const float*)d_in[4];
    const float* b1   = (const float*)d_in[5];
    const float* W2   = (const float*)d_in[6];
    const float* b2   = (const float*)d_in[7];
    const float* W3   = (const float*)d_in[8];
    const float* b3   = (const float*)d_in[9];
    const float* WR   = (const float*)d_in[10];
    const float* bR   = (const float*)d_in[11];
    const float* Vw   = (const float*)d_in[12];
    const float* Vb   = (const float*)d_in[13];
    const float* Wq   = (const float*)d_in[14];
    const float* bq   = (const float*)d_in[15];
    const float* Wk   = (const float*)d_in[16];
    const float* bk   = (const float*)d_in[17];
    const float* Wv   = (const float*)d_in[18];
    const float* bv   = (const float*)d_in[19];
    const float* Wo   = (const float*)d_in[20];
    const float* bo   = (const float*)d_in[21];

    float* ws = (float*)d_ws;
    float* dout = (float*)d_out;

    float* xf    = ws + OFF_X;
    float* cur1  = ws + OFF_CUR1;
    float* mem1a = ws + OFF_MEM1;
    float* mem2a = ws + OFF_MEM2;
    float* mem3a = ws + OFF_MEM3;
    float* memra = ws + OFF_MEMR;
    float* spkra = ws + OFF_SPKR;
    float* memo  = ws + OFF_MEMO;
    float* patt  = ws + OFF_PATT;
    float* cntb  = ws + OFF_CNT;
    float* oacc  = ws + OFF_OACC;
    float* sc    = ws + OFF_SC;
    unsigned int* tick = (unsigned int*)(ws + OFF_TICK);
    float* part  = ws + OFF_PART;
    float* pg2   = ws + OFF_PG2;
    float* pg3   = ws + OFF_PG3;
    float* pkk   = ws + OFF_PKK;
    float* pvv   = ws + OFF_PVV;
    float* mem2b = ws + OFF_M2B;
    float* mem3b = ws + OFF_M3B;
    float* mem1b = ws + OFF_M1B;
    float* spk1  = ws + OFF_SPK1;
    float* memrb = ws + OFF_MRB;
    float* spkrb = ws + OFF_SRB;

    // chunk count for the big GEMM: cap 365 (tpc=2) -> 730 blocks, 46.7 MB partials
    size_t ws_f = ws_size / 4;
    size_t avail = (ws_f > OFF_PART) ? (ws_f - OFF_PART) : 0;
    long nchunk_l = (long)(avail / 32000);
    int nchunk = (nchunk_l > 365) ? 365 : (int)nchunk_l;
    if (nchunk < 1) nchunk = 1;
    int tpc = (729 + nchunk - 1) / nchunk;
    nchunk = (729 + tpc - 1) / tpc;

    k_init<<<402, 256, 0, stream>>>(ws);
    k_patch<<<dim3(32, 27), 64, 0, stream>>>(data, Wpe, bpe, pos, xf);
    k_gemm1_part<<<dim3(nchunk, 2), 256, 0, stream>>>(xf, W1, part, tpc);
    k_gemm1_reduce<<<250, 128, 0, stream>>>(part, b1, cur1, nchunk);

    for (int t = 0; t < 5; ++t) {
        float* cnt = cntb + t * 4;
        float* m1o = (t & 1) ? mem1b : mem1a;
        float* m1n = (t & 1) ? mem1a : mem1b;
        float* m2o = (t & 1) ? mem2b : mem2a;
        float* m2n = (t & 1) ? mem2a : mem2b;
        float* m3o = (t & 1) ? mem3b : mem3a;
        float* m3n = (t & 1) ? mem3a : mem3b;
        float* mro = (t & 1) ? memrb : memra;
        float* mrn = (t & 1) ? memra : memrb;
        float* sro = (t & 1) ? spkrb : spkra;
        float* srn = (t & 1) ? spkra : spkrb;

        // 1. double-leaky (in staging) + GEMM @ W2 -> pg2
        k_gsp<<<dim3(8, 25, 8), 256, 0, stream>>>(
            cur1, m1o, m1n, spk1, W2, pg2, cnt + 0);
        // 2. reduce pg2 + leaky(mem2) staged, GEMM @ W3 -> pg3
        k_gspred<false><<<dim3(8, 25, 8), 256, 0, stream>>>(
            pg2, b2, m2o, m2n, W3, pg3, nullptr);
        // 3. reduce pg3 + leaky(mem3)(+count) staged, GEMM @ Wk/Wv -> pkk, pvv
        k_gspred_kv<<<dim3(8, 25, 8), 256, 0, stream>>>(
            pg3, b3, m3o, m3n, Wk, Wv, pkk, pvv, cnt + 1);
        // 4. attention: RLeaky prologue + K/V reduce + q + softmax + final
        k_attnred<<<dim3(8, 32), 512, 0, stream>>>(
            pkk, pvv, bk, bv, spk1, WR, bR, Vw, Vb,
            mro, mrn, sro, srn, Wq, bq, Wo, bo,
            patt, memo, oacc, cnt, sc, dout, tick + t, cnt + 2, t);
    }
    (void)in_sizes; (void)n_in; (void)out_size;
}

// Round 16
// 480.085 us; speedup vs baseline: 1.1055x; 1.0267x over previous
//
#include <hip/hip_runtime.h>

// ---------------- workspace layout (float offsets) ----------------
#define OFF_X     0          // x_flat [32][46656]
#define OFF_CUR1  1492992    // [32][1000]
#define OFF_MEM1  1524992    // [32][1000]  (slot A)
#define OFF_MEM2  1556992    // [32][1000]  (slot A)
#define OFF_MEM3  1588992    // [32][1000]  (slot A)
#define OFF_MEMR  1844992    // [32][100]   (slot A)
#define OFF_SPKR  1848192    // [32][100]   (slot A)
#define OFF_MEMO  1851392    // [32]
#define OFF_PATT  1851424    // [32][8]
#define OFF_CNT   1851680    // [5][4] spike counters
#define OFF_OACC  1851700    // [32]
#define OFF_SC    1851732    // total, reg
#define OFF_TICK  1851736    // [5] uint ticket counters (one per step)
#define OFF_PART  1851744    // gemm1 partials [nchunk<=365][32][1000]
// step-loop buffers (overlay the gemm1 partial region after it's consumed)
#define OFF_PG2   OFF_PART               // [25][32][1000]
#define OFF_PG3   (OFF_PART + 800000)    // [25][32][1000]
#define OFF_PKK   (OFF_PART + 1600000)   // [25][32][1000]
#define OFF_PVV   (OFF_PART + 2400000)   // [25][32][1000]
#define OFF_M2B   (OFF_PART + 3200000)   // [32][1000] mem2 slot B
#define OFF_M3B   (OFF_PART + 3232000)   // [32][1000] mem3 slot B
#define OFF_M1B   (OFF_PART + 3264000)   // [32][1000] mem1 slot B
#define OFF_SPK1  (OFF_PART + 3296000)   // [32][1000] spk1 (first leaky spike)
#define OFF_MRB   (OFF_PART + 3328000)   // [32][100] memr slot B
#define OFF_SRB   (OFF_PART + 3331200)   // [32][100] spkr slot B

static constexpr float kBETA  = 0.8f;
static constexpr float kTHR   = 0.5f;
static constexpr float kBETAR = 0.95f;
static constexpr float kTHRR  = 1.0f;
static constexpr float kLM    = 0.0058f;

// ---------------- init: zero all persistent state ----------------
__global__ void k_init(float* ws) {
    int idx = blockIdx.x * 256 + threadIdx.x;
    if (idx < 96000) {
        ws[OFF_MEM1 + idx] = 0.f;                 // mem1, mem2, mem3 (slot A)
    } else {
        int j = idx - 96000;
        if (j < 6752) ws[OFF_MEMR + j] = 0.f;     // memr/spkr A .. sc + tick
    }
}

// ---------------- patch embed: one block per (batch, patch-row) ----------------
__global__ __launch_bounds__(64) void k_patch(
    const float* __restrict__ data, const float* __restrict__ Wpe,
    const float* __restrict__ bpe, const float* __restrict__ pos,
    float* __restrict__ xf)
{
    int b = blockIdx.x, pr = blockIdx.y;
    int tid = threadIdx.x;
    const float* db = data + (size_t)b * 50176 + pr * 1792;  // input row pr*8
    float bb = bpe[tid];
    float acc[27];
    #pragma unroll
    for (int pc = 0; pc < 27; ++pc)
        acc[pc] = bb + pos[(pr * 27 + pc) * 64 + tid];
    #pragma unroll 2
    for (int c = 0; c < 256; ++c) {
        float w = Wpe[c * 64 + tid];
        const float* row = db + (c >> 4) * 224 + (c & 15);
        #pragma unroll
        for (int pc = 0; pc < 27; ++pc)
            acc[pc] = fmaf(row[pc * 8], w, acc[pc]);
    }
    size_t obase = (size_t)b * 46656 + (size_t)pr * 27 * 64 + tid;
    #pragma unroll
    for (int pc = 0; pc < 27; ++pc)
        xf[obase + (size_t)pc * 64] = acc[pc];
}

// ---------------- big GEMM partials: W1 once, ADJACENT h-pair per thread ----------------
// float2 W loads: 4 loads per ii4 (was 8 scalar) -> half the VMEM issue slots.
// Per-output FMA order identical (each h accumulates over i in the same sequence).
__global__ __launch_bounds__(256) void k_gemm1_part(
    const float* __restrict__ xf, const float* __restrict__ W1,
    float* __restrict__ part, int tpc)
{
    int chunk = blockIdx.x;
    int hg = blockIdx.y;
    int t0 = chunk * tpc;
    int t1 = t0 + tpc; if (t1 > 729) t1 = 729;
    int tid = threadIdx.x;
    __shared__ float xs[2048];           // [32 b][64 i]
    float acc[32][2];
    #pragma unroll
    for (int b = 0; b < 32; ++b) { acc[b][0] = 0.f; acc[b][1] = 0.f; }

    const int hbase = hg * 500;
    const bool ok = tid < 250;           // h pair (hbase+2*tid, +1)
    const int hp = ok ? 2 * tid : 0;
    for (int tt = t0; tt < t1; ++tt) {
        int i0 = tt * 64;
        __syncthreads();
        for (int l = tid; l < 2048; l += 256)
            xs[l] = xf[(size_t)(l >> 6) * 46656 + i0 + (l & 63)];
        __syncthreads();
        for (int ii4 = 0; ii4 < 16; ++ii4) {
            int i = i0 + ii4 * 4;
            const float* base = W1 + (size_t)i * 1000 + hbase + hp;
            float2 w0 = ok ? *reinterpret_cast<const float2*>(base)
                           : make_float2(0.f, 0.f);
            float2 w1 = ok ? *reinterpret_cast<const float2*>(base + 1000)
                           : make_float2(0.f, 0.f);
            float2 w2 = ok ? *reinterpret_cast<const float2*>(base + 2000)
                           : make_float2(0.f, 0.f);
            float2 w3 = ok ? *reinterpret_cast<const float2*>(base + 3000)
                           : make_float2(0.f, 0.f);
            #pragma unroll
            for (int b = 0; b < 32; ++b) {
                float4 xv = *reinterpret_cast<const float4*>(&xs[b * 64 + ii4 * 4]);
                float a0 = acc[b][0], a1 = acc[b][1];
                a0 = fmaf(xv.x, w0.x, a0);  a1 = fmaf(xv.x, w0.y, a1);
                a0 = fmaf(xv.y, w1.x, a0);  a1 = fmaf(xv.y, w1.y, a1);
                a0 = fmaf(xv.z, w2.x, a0);  a1 = fmaf(xv.z, w2.y, a1);
                a0 = fmaf(xv.w, w3.x, a0);  a1 = fmaf(xv.w, w3.y, a1);
                acc[b][0] = a0; acc[b][1] = a1;
            }
        }
    }
    if (ok) {
        float* pc = part + (size_t)chunk * 32000 + hbase + hp;
        #pragma unroll
        for (int b = 0; b < 32; ++b)
            *reinterpret_cast<float2*>(&pc[b * 1000]) = make_float2(acc[b][0], acc[b][1]);
    }
}

// ---------------- reduce with 8-way ILP on the chunk chain ----------------
__global__ void k_gemm1_reduce(const float* __restrict__ part,
                               const float* __restrict__ b1,
                               float* __restrict__ cur1, int nchunk)
{
    int idx = blockIdx.x * 128 + threadIdx.x;   // 250 blocks x 128
    if (idx >= 32000) return;
    int h = idx % 1000;
    float a0 = b1[h], a1 = 0.f, a2 = 0.f, a3 = 0.f;
    float a4 = 0.f, a5 = 0.f, a6 = 0.f, a7 = 0.f;
    int c = 0;
    for (; c + 8 <= nchunk; c += 8) {
        a0 += part[(size_t)c * 32000 + idx];
        a1 += part[(size_t)(c + 1) * 32000 + idx];
        a2 += part[(size_t)(c + 2) * 32000 + idx];
        a3 += part[(size_t)(c + 3) * 32000 + idx];
        a4 += part[(size_t)(c + 4) * 32000 + idx];
        a5 += part[(size_t)(c + 5) * 32000 + idx];
        a6 += part[(size_t)(c + 6) * 32000 + idx];
        a7 += part[(size_t)(c + 7) * 32000 + idx];
    }
    for (; c < nchunk; ++c) a0 += part[(size_t)c * 32000 + idx];
    cur1[idx] = ((a0 + a1) + (a2 + a3)) + ((a4 + a5) + (a6 + a7));
}

// ---------------- layer-1 GEMM with double-leaky computed in staging ----------------
__global__ __launch_bounds__(256) void k_gsp(
    const float* __restrict__ cur1, const float* __restrict__ mem1_old,
    float* __restrict__ mem1_new, float* __restrict__ spk1_out,
    const float* __restrict__ W, float* __restrict__ part, float* cnt0)
{
    int hb = blockIdx.x, kc = blockIdx.y, bg = blockIdx.z;
    int tid = threadIdx.x;
    int j0 = kc * 40;
    __shared__ __align__(16) float al[160];      // [40 jj][4 b]
    __shared__ float redg[4 * 128];
    __shared__ float csum[4];
    float localc = 0.f;
    if (tid < 160) {
        int jj = tid % 40, bi = tid / 40;
        int idx = (bg * 4 + bi) * 1000 + j0 + jj;
        float m = mem1_old[idx], c = cur1[idx];
        float r1 = (m - kTHR > 0.f) ? kTHR : 0.f;
        float ma = __fsub_rn(__fadd_rn(__fmul_rn(kBETA, m), c), r1);
        float s1 = (ma - kTHR > 0.f) ? 1.f : 0.f;
        float r2 = __fmul_rn(s1, kTHR);
        float mb = __fsub_rn(__fadd_rn(__fmul_rn(kBETA, ma), c), r2);
        float s1b = (mb - kTHR > 0.f) ? 1.f : 0.f;
        al[jj * 4 + bi] = s1b;
        if (hb == 0) { mem1_new[idx] = mb; spk1_out[idx] = s1; localc = s1; }
    }
    for (int off = 32; off; off >>= 1) localc += __shfl_down(localc, off, 64);
    if ((tid & 63) == 0) csum[tid >> 6] = localc;
    __syncthreads();
    if (hb == 0 && tid == 0) {
        float tot = csum[0] + csum[1] + csum[2] + csum[3];
        if (tot != 0.f) atomicAdd(cnt0, tot);
    }
    int ks = tid >> 7, hh = tid & 127;
    float acc[4] = {0.f, 0.f, 0.f, 0.f};
    if (hh < 125) {
        int h = hb * 125 + hh;
        const float* Wp = W + (size_t)(j0 + ks * 20) * 1000 + h;
        const float4* abase = reinterpret_cast<const float4*>(&al[ks * 20 * 4]);
        #pragma unroll 4
        for (int jj = 0; jj < 20; ++jj) {
            float w = Wp[(size_t)jj * 1000];
            float4 av = abase[jj];
            acc[0] = fmaf(av.x, w, acc[0]);
            acc[1] = fmaf(av.y, w, acc[1]);
            acc[2] = fmaf(av.z, w, acc[2]);
            acc[3] = fmaf(av.w, w, acc[3]);
        }
    }
    if (ks == 1 && hh < 125) {
        #pragma unroll
        for (int b = 0; b < 4; ++b) redg[b * 128 + hh] = acc[b];
    }
    __syncthreads();
    if (ks == 0 && hh < 125) {
        int h = hb * 125 + hh;
        float* pp = part + (size_t)kc * 32000 + (size_t)(bg * 4) * 1000 + h;
        #pragma unroll
        for (int b = 0; b < 4; ++b) pp[(size_t)b * 1000] = acc[b] + redg[b * 128 + hh];
    }
}

// ---------------- reduce(prev partials)+leaky staged in LDS, then split GEMM ----------------
template <bool COUNT>
__global__ __launch_bounds__(256) void k_gspred(
    const float* __restrict__ pin, const float* __restrict__ bias,
    const float* __restrict__ mem_old, float* __restrict__ mem_new,
    const float* __restrict__ W, float* __restrict__ pout, float* cnt)
{
    int hs = blockIdx.x, kc = blockIdx.y, bg = blockIdx.z;
    int tid = threadIdx.x;
    int j0 = kc * 40;
    __shared__ __align__(16) float al[160];
    __shared__ float redg[4 * 128];
    __shared__ float csum[4];
    float localc = 0.f;
    if (tid < 160) {
        int jj = tid % 40, bi = tid / 40;
        int idx = (bg * 4 + bi) * 1000 + j0 + jj;
        float a = bias[j0 + jj];
        #pragma unroll 5
        for (int c = 0; c < 25; ++c) a += pin[(size_t)c * 32000 + idx];
        float m = mem_old[idx];
        float r = (m - kTHR > 0.f) ? kTHR : 0.f;
        float mn = __fsub_rn(__fadd_rn(__fmul_rn(kBETA, m), a), r);
        float s = (mn - kTHR > 0.f) ? 1.f : 0.f;
        al[jj * 4 + bi] = s;
        if (hs == 0) { mem_new[idx] = mn; localc = s; }
    }
    if (COUNT) {
        for (int off = 32; off; off >>= 1) localc += __shfl_down(localc, off, 64);
        if ((tid & 63) == 0) csum[tid >> 6] = localc;
    }
    __syncthreads();
    if (COUNT && tid == 0 && hs == 0) {
        float tot = csum[0] + csum[1] + csum[2] + csum[3];
        if (tot != 0.f) atomicAdd(cnt, tot);
    }
    int ks = tid >> 7, hh = tid & 127;
    float acc[4] = {0.f, 0.f, 0.f, 0.f};
    if (hh < 125) {
        int h = hs * 125 + hh;
        const float* Wp = W + (size_t)(j0 + ks * 20) * 1000 + h;
        const float4* abase = reinterpret_cast<const float4*>(&al[ks * 20 * 4]);
        #pragma unroll 4
        for (int jj = 0; jj < 20; ++jj) {
            float w = Wp[(size_t)jj * 1000];
            float4 av = abase[jj];
            acc[0] = fmaf(av.x, w, acc[0]);
            acc[1] = fmaf(av.y, w, acc[1]);
            acc[2] = fmaf(av.z, w, acc[2]);
            acc[3] = fmaf(av.w, w, acc[3]);
        }
    }
    if (ks == 1 && hh < 125) {
        #pragma unroll
        for (int b = 0; b < 4; ++b) redg[b * 128 + hh] = acc[b];
    }
    __syncthreads();
    if (ks == 0 && hh < 125) {
        int h = hs * 125 + hh;
        float* pp = pout + (size_t)kc * 32000 + (size_t)(bg * 4) * 1000 + h;
        #pragma unroll
        for (int b = 0; b < 4; ++b) pp[(size_t)b * 1000] = acc[b] + redg[b * 128 + hh];
    }
}

// dual-weight variant: layer-3 reduce+leaky(+count) staged, then K and V partials
__global__ __launch_bounds__(256) void k_gspred_kv(
    const float* __restrict__ pin, const float* __restrict__ bias,
    const float* __restrict__ mem_old, float* __restrict__ mem_new,
    const float* __restrict__ Wk, const float* __restrict__ Wv,
    float* __restrict__ pk, float* __restrict__ pv, float* cnt)
{
    int hs = blockIdx.x, kc = blockIdx.y, bg = blockIdx.z;
    int tid = threadIdx.x;
    int j0 = kc * 40;
    __shared__ __align__(16) float al[160];
    __shared__ float redk[4 * 128];
    __shared__ float redv[4 * 128];
    __shared__ float csum[4];
    float localc = 0.f;
    if (tid < 160) {
        int jj = tid % 40, bi = tid / 40;
        int idx = (bg * 4 + bi) * 1000 + j0 + jj;
        float a = bias[j0 + jj];
        #pragma unroll 5
        for (int c = 0; c < 25; ++c) a += pin[(size_t)c * 32000 + idx];
        float m = mem_old[idx];
        float r = (m - kTHR > 0.f) ? kTHR : 0.f;
        float mn = __fsub_rn(__fadd_rn(__fmul_rn(kBETA, m), a), r);
        float s = (mn - kTHR > 0.f) ? 1.f : 0.f;
        al[jj * 4 + bi] = s;
        if (hs == 0) { mem_new[idx] = mn; localc = s; }
    }
    for (int off = 32; off; off >>= 1) localc += __shfl_down(localc, off, 64);
    if ((tid & 63) == 0) csum[tid >> 6] = localc;
    __syncthreads();
    if (tid == 0 && hs == 0) {
        float tot = csum[0] + csum[1] + csum[2] + csum[3];
        if (tot != 0.f) atomicAdd(cnt, tot);
    }
    int ks = tid >> 7, hh = tid & 127;
    float ak[4] = {0.f, 0.f, 0.f, 0.f};
    float av2[4] = {0.f, 0.f, 0.f, 0.f};
    if (hh < 125) {
        int h = hs * 125 + hh;
        const float* wkp = Wk + (size_t)(j0 + ks * 20) * 1000 + h;
        const float* wvp = Wv + (size_t)(j0 + ks * 20) * 1000 + h;
        const float4* abase = reinterpret_cast<const float4*>(&al[ks * 20 * 4]);
        #pragma unroll 4
        for (int jj = 0; jj < 20; ++jj) {
            float wk = wkp[(size_t)jj * 1000];
            float wv = wvp[(size_t)jj * 1000];
            float4 av = abase[jj];
            ak[0] = fmaf(av.x, wk, ak[0]);  av2[0] = fmaf(av.x, wv, av2[0]);
            ak[1] = fmaf(av.y, wk, ak[1]);  av2[1] = fmaf(av.y, wv, av2[1]);
            ak[2] = fmaf(av.z, wk, ak[2]);  av2[2] = fmaf(av.z, wv, av2[2]);
            ak[3] = fmaf(av.w, wk, ak[3]);  av2[3] = fmaf(av.w, wv, av2[3]);
        }
    }
    if (ks == 1 && hh < 125) {
        #pragma unroll
        for (int b = 0; b < 4; ++b) { redk[b * 128 + hh] = ak[b]; redv[b * 128 + hh] = av2[b]; }
    }
    __syncthreads();
    if (ks == 0 && hh < 125) {
        int h = hs * 125 + hh;
        float* ppk = pk + (size_t)kc * 32000 + (size_t)(bg * 4) * 1000 + h;
        float* ppv = pv + (size_t)kc * 32000 + (size_t)(bg * 4) * 1000 + h;
        #pragma unroll
        for (int b = 0; b < 4; ++b) {
            ppk[(size_t)b * 1000] = ak[b] + redk[b * 128 + hh];
            ppv[(size_t)b * 1000] = av2[b] + redv[b * 128 + hh];
        }
    }
}

// ---------------- attention: K/V reduce overlapped with RLeaky staging ----------------
// Phase A packs s1l/sr staging AND the K/V 25-chunk reduce (independent loads -> MLP).
__global__ __launch_bounds__(512) void k_attnred(
    const float* __restrict__ pkk, const float* __restrict__ pvv,
    const float* __restrict__ bk, const float* __restrict__ bv,
    const float* __restrict__ spk1, const float* __restrict__ WR,
    const float* __restrict__ bR, const float* __restrict__ Vw,
    const float* __restrict__ Vb,
    const float* __restrict__ memr_old, float* __restrict__ memr_new,
    const float* __restrict__ spkr_old, float* __restrict__ spkr_new,
    const float* __restrict__ Wq, const float* __restrict__ bq,
    const float* __restrict__ Wo, const float* __restrict__ bo,
    float* __restrict__ patt, float* __restrict__ memo,
    float* __restrict__ oacc, const float* __restrict__ cnt,
    float* __restrict__ sc, float* __restrict__ dout,
    unsigned int* __restrict__ tick, float* cnt2, int t)
{
    int it = blockIdx.x, b = blockIdx.y;
    int tid = threadIdx.x;
    __shared__ float kk[1000], vv[1000];
    __shared__ float sr[100];
    __shared__ float s1l[1000];
    __shared__ float red2[512];
    __shared__ float pden[512], pnum[512];
    __shared__ float wred[8], wred2[8];
    __shared__ int isLast;

    // ---- Phase A: stage s1l + sr, AND K/V reduce (independent; overlapped) ----
    for (int l = tid; l < 1000; l += 512) s1l[l] = spk1[b * 1000 + l];
    if (tid < 100) sr[tid] = spkr_old[b * 100 + tid];
    float pmax = -3.4e38f, pmin = 3.4e38f;
    for (int h = tid; h < 1000; h += 512) {
        int idx = b * 1000 + h;
        float ak = bk[h], av = bv[h];
        #pragma unroll 5
        for (int c = 0; c < 25; ++c) {
            ak += pkk[(size_t)c * 32000 + idx];
            av += pvv[(size_t)c * 32000 + idx];
        }
        kk[h] = ak; vv[h] = av;
        pmax = fmaxf(pmax, ak);
        pmin = fminf(pmin, ak);
    }
    for (int off = 32; off; off >>= 1) {
        pmax = fmaxf(pmax, __shfl_down(pmax, off, 64));
        pmin = fminf(pmin, __shfl_down(pmin, off, 64));
    }
    if ((tid & 63) == 0) { wred[tid >> 6] = pmax; wred2[tid >> 6] = pmin; }
    __syncthreads();

    // ---- Phase B: WR GEMM (4-way 250-chain split, R12 order) ----
    int ks4 = tid >> 7, hh4 = tid & 127;
    float p = 0.f;
    if (hh4 < 100) {
        const float* wp = WR + (size_t)(ks4 * 250) * 100 + hh4;
        int j0r = ks4 * 250;
        #pragma unroll 5
        for (int j = 0; j < 250; ++j) p = fmaf(s1l[j0r + j], wp[(size_t)j * 100], p);
    }
    red2[ks4 * 128 + hh4] = p;
    __syncthreads();

    // ---- Phase C: RLeaky update (tid<100) ----
    float snew = 0.f;
    if (tid < 100) {
        float acc = bR[tid] + ((red2[tid] + red2[128 + tid]) + (red2[256 + tid] + red2[384 + tid]));
        float rec = 0.f;
        for (int j = 0; j < 100; ++j) rec = fmaf(sr[j], Vw[j * 100 + tid], rec);
        float m = memr_old[b * 100 + tid];
        float r = (m - kTHRR > 0.f) ? kTHRR : 0.f;
        float mn = __fsub_rn(__fadd_rn(__fadd_rn(__fadd_rn(__fmul_rn(kBETAR, m), acc), rec), Vb[tid]), r);
        snew = (mn - kTHRR > 0.f) ? 1.f : 0.f;
        if (it == 0) { memr_new[b * 100 + tid] = mn; spkr_new[b * 100 + tid] = snew; }
    }
    if (it == 0) {
        unsigned long long mskr = __ballot(snew > 0.5f);
        if ((tid & 63) == 0) {
            int pc2 = __popcll(mskr);
            if (pc2) atomicAdd(cnt2, (float)pc2);
        }
    }
    __syncthreads();
    if (tid < 100) sr[tid] = snew;     // sr now holds spkr_new for the q-GEMM
    __syncthreads();

    float kmax = wred[0], kmin = wred2[0];
    #pragma unroll
    for (int w = 1; w < 8; ++w) {
        kmax = fmaxf(kmax, wred[w]);
        kmin = fminf(kmin, wred2[w]);
    }

    // ---- 4-way split softmax ----
    int quarter = tid >> 7, lane = tid & 127;
    float den = 0.f, num = 0.f;
    if (lane < 125) {
        int i = it * 125 + lane;
        float qi = bq[i];
        for (int j = 0; j < 100; ++j) qi = fmaf(sr[j], Wq[j * 1000 + i], qi);
        float qs = qi / 31.62277660168379f;   // sqrt(1000)
        float m = (qs >= 0.f) ? qs * kmax : qs * kmin;
        int jb = quarter * 250;
        for (int j = 0; j < 250; ++j) {
            float e = __expf(fmaf(qs, kk[jb + j], -m));
            den += e;
            num = fmaf(e, vv[jb + j], num);
        }
    }
    pden[tid] = den; pnum[tid] = num;
    __syncthreads();
    float pw = 0.f;
    if (tid < 125) {
        float dsum = (pden[tid] + pden[tid + 128]) + (pden[tid + 256] + pden[tid + 384]);
        float nsum = (pnum[tid] + pnum[tid + 128]) + (pnum[tid + 256] + pnum[tid + 384]);
        pw = (nsum / dsum) * Wo[it * 125 + tid];
    }
    for (int off = 32; off; off >>= 1) pw += __shfl_down(pw, off, 64);
    if ((tid & 63) == 0) wred[tid >> 6] = pw;
    __syncthreads();
    if (tid == 0) {
        float tot = ((wred[0] + wred[1]) + (wred[2] + wred[3]))
                  + ((wred[4] + wred[5]) + (wred[6] + wred[7]));
        patt[b * 8 + it] = tot;
    }
    __syncthreads();
    if (tid == 0) {
        __threadfence();
        unsigned r = atomicAdd(tick, 1u);
        isLast = (r == 255u) ? 1 : 0;
    }
    __syncthreads();
    if (isLast && tid < 64) {
        __threadfence();
        float s = 0.f;
        if (tid < 32) {
            float a = bo[0];
            for (int itx = 0; itx < 8; ++itx) a += patt[tid * 8 + itx];
            float m = memo[tid];
            float r = (m - kTHR > 0.f) ? kTHR : 0.f;
            float mn = __fsub_rn(__fadd_rn(__fmul_rn(kBETA, m), a), r);
            memo[tid] = mn;
            s = (mn - kTHR > 0.f) ? 1.f : 0.f;
            float oa = oacc[tid] + s;
            oacc[tid] = oa;
            if (t == 4) dout[tid] = oa / 5.0f;
        }
        unsigned long long msk = __ballot(s > 0.5f);
        float co = (float)__popcll(msk);
        if (tid == 0) {
            float total = sc[0];
            float prev = total;
            total = __fadd_rn(total, __fdiv_rn(cnt[0], 32000.f));
            total = __fadd_rn(total, __fdiv_rn(cnt[1], 32000.f));
            total = __fadd_rn(total, __fdiv_rn(cnt[2], 3200.f));
            total = __fadd_rn(total, __fdiv_rn(co, 32.f));
            float reg = sc[1];
            reg = __fadd_rn(reg, __fmul_rn(kLM, total));
            if (t > 0) reg = __fadd_rn(reg, __fmul_rn(kLM, fabsf(__fsub_rn(total, prev))));
            sc[0] = total; sc[1] = reg;
            if (t == 4) dout[32] = reg / 5.0f;
        }
    }
}

// ---------------- host ----------------
extern "C" void kernel_launch(void* const* d_in, const int* in_sizes, int n_in,
                              void* d_out, int out_size, void* d_ws, size_t ws_size,
                              hipStream_t stream)
{
    const float* data = (const float*)d_in[0];
    const float* Wpe  = (const float*)d_in[1];
    const float* bpe  = (const float*)d_in[2];
    const float* pos  = (const float*)d_in[3];
    const float* W1   = (const float*)d_in[4];
    const float* b1   = (const float*)d_in[5];
    const float* W2   = (const float*)d_in[6];
    const float* b2   = (const float*)d_in[7];
    const float* W3   = (const float*)d_in[8];
    const float* b3   = (const float*)d_in[9];
    const float* WR   = (const float*)d_in[10];
    const float* bR   = (const float*)d_in[11];
    const float* Vw   = (const float*)d_in[12];
    const float* Vb   = (const float*)d_in[13];
    const float* Wq   = (const float*)d_in[14];
    const float* bq   = (const float*)d_in[15];
    const float* Wk   = (const float*)d_in[16];
    const float* bk   = (const float*)d_in[17];
    const float* Wv   = (const float*)d_in[18];
    const float* bv   = (const float*)d_in[19];
    const float* Wo   = (const float*)d_in[20];
    const float* bo   = (const float*)d_in[21];

    float* ws = (float*)d_ws;
    float* dout = (float*)d_out;

    float* xf    = ws + OFF_X;
    float* cur1  = ws + OFF_CUR1;
    float* mem1a = ws + OFF_MEM1;
    float* mem2a = ws + OFF_MEM2;
    float* mem3a = ws + OFF_MEM3;
    float* memra = ws + OFF_MEMR;
    float* spkra = ws + OFF_SPKR;
    float* memo  = ws + OFF_MEMO;
    float* patt  = ws + OFF_PATT;
    float* cntb  = ws + OFF_CNT;
    float* oacc  = ws + OFF_OACC;
    float* sc    = ws + OFF_SC;
    unsigned int* tick = (unsigned int*)(ws + OFF_TICK);
    float* part  = ws + OFF_PART;
    float* pg2   = ws + OFF_PG2;
    float* pg3   = ws + OFF_PG3;
    float* pkk   = ws + OFF_PKK;
    float* pvv   = ws + OFF_PVV;
    float* mem2b = ws + OFF_M2B;
    float* mem3b = ws + OFF_M3B;
    float* mem1b = ws + OFF_M1B;
    float* spk1  = ws + OFF_SPK1;
    float* memrb = ws + OFF_MRB;
    float* spkrb = ws + OFF_SRB;

    // chunk count for the big GEMM: cap 365 (tpc=2) -> 730 blocks, 46.7 MB partials
    size_t ws_f = ws_size / 4;
    size_t avail = (ws_f > OFF_PART) ? (ws_f - OFF_PART) : 0;
    long nchunk_l = (long)(avail / 32000);
    int nchunk = (nchunk_l > 365) ? 365 : (int)nchunk_l;
    if (nchunk < 1) nchunk = 1;
    int tpc = (729 + nchunk - 1) / nchunk;
    nchunk = (729 + tpc - 1) / tpc;

    k_init<<<402, 256, 0, stream>>>(ws);
    k_patch<<<dim3(32, 27), 64, 0, stream>>>(data, Wpe, bpe, pos, xf);
    k_gemm1_part<<<dim3(nchunk, 2), 256, 0, stream>>>(xf, W1, part, tpc);
    k_gemm1_reduce<<<250, 128, 0, stream>>>(part, b1, cur1, nchunk);

    for (int t = 0; t < 5; ++t) {
        float* cnt = cntb + t * 4;
        float* m1o = (t & 1) ? mem1b : mem1a;
        float* m1n = (t & 1) ? mem1a : mem1b;
        float* m2o = (t & 1) ? mem2b : mem2a;
        float* m2n = (t & 1) ? mem2a : mem2b;
        float* m3o = (t & 1) ? mem3b : mem3a;
        float* m3n = (t & 1) ? mem3a : mem3b;
        float* mro = (t & 1) ? memrb : memra;
        float* mrn = (t & 1) ? memra : memrb;
        float* sro = (t & 1) ? spkrb : spkra;
        float* srn = (t & 1) ? spkra : spkrb;

        // 1. double-leaky (in staging) + GEMM @ W2 -> pg2
        k_gsp<<<dim3(8, 25, 8), 256, 0, stream>>>(
            cur1, m1o, m1n, spk1, W2, pg2, cnt + 0);
        // 2. reduce pg2 + leaky(mem2) staged, GEMM @ W3 -> pg3
        k_gspred<false><<<dim3(8, 25, 8), 256, 0, stream>>>(
            pg2, b2, m2o, m2n, W3, pg3, nullptr);
        // 3. reduce pg3 + leaky(mem3)(+count) staged, GEMM @ Wk/Wv -> pkk, pvv
        k_gspred_kv<<<dim3(8, 25, 8), 256, 0, stream>>>(
            pg3, b3, m3o, m3n, Wk, Wv, pkk, pvv, cnt + 1);
        // 4. attention: overlapped RLeaky/KV + q + softmax + final
        k_attnred<<<dim3(8, 32), 512, 0, stream>>>(
            pkk, pvv, bk, bv, spk1, WR, bR, Vw, Vb,
            mro, mrn, sro, srn, Wq, bq, Wo, bo,
            patt, memo, oacc, cnt, sc, dout, tick + t, cnt + 2, t);
    }
    (void)in_sizes; (void)n_in; (void)out_size;
}